// Round 3
// baseline (174.807 us; speedup 1.0000x reference)
//
#include <hip/hip_runtime.h>
#include <math.h>

#define N_TOK 16384
#define DM    4096
#define DH    2048
#define NE    64
#define TB    32        // tokens per block
#define TOPK  4
#define KQ    1024      // k-range per wave within its half
#define NSTEP 32        // KQ / 32

// out layout (all float32): topk_i [N,4] | topk_s [N,4] | scores [N,64] | aux_loss [1]
#define OFF_TI  0
#define OFF_TS  (N_TOK * TOPK)
#define OFF_SC  (N_TOK * TOPK * 2)
#define OFF_AUX (N_TOK * TOPK * 2 + N_TOK * NE)

typedef __attribute__((ext_vector_type(4))) float  f32x4;
typedef __attribute__((ext_vector_type(8))) __bf16 bf16x8;

// ws layout: __bf16 Bsplit[2 halves][3 splits][64 e][2048 k] (1.5 MB), then float esum[64]
#define BSPLIT_ELEMS (2 * 3 * NE * DH)

__device__ __forceinline__ void split3(float a, __bf16& h, __bf16& m, __bf16& l) {
    h = (__bf16)a;                 // RNE; a = h+m+l is an EXACT decomposition (24 = 8+8+8 bits)
    float r = a - (float)h;        // exact (Sterbenz)
    m = (__bf16)r;
    float r2 = r - (float)m;       // exact
    l = (__bf16)r2;                // exact (<=8 significant bits left)
}

// Pre-split + transpose E into ws: Bws[(half*3+s)*64 + e][k] bf16, k contiguous.
__global__ __launch_bounds__(256) void prep_B(
    const float* __restrict__ Ex, const float* __restrict__ Ey,
    __bf16* __restrict__ Bws)
{
    __shared__ float te[128][68];
    const int tid  = threadIdx.x;
    const int half = blockIdx.x >> 4;
    const int k0   = (blockIdx.x & 15) * 128;
    const float* E = half ? Ey : Ex;
    #pragma unroll
    for (int i = 0; i < 8; ++i) {                    // 128x64 fp32 tile, coalesced
        int idx = tid + 256 * i;                     // float4 index
        int row = idx >> 4, c4 = idx & 15;
        f32x4 v = *(const f32x4*)(E + (size_t)(k0 + row) * NE + c4 * 4);
        *(f32x4*)&te[row][c4 * 4] = v;
    }
    __syncthreads();
    const int e  = tid >> 2;
    const int kl = (tid & 3) * 32;
    bf16x8 vh[4], vm[4], vl[4];
    #pragma unroll
    for (int g = 0; g < 4; ++g)
        #pragma unroll
        for (int j = 0; j < 8; ++j) {
            __bf16 h, m, l;
            split3(te[kl + g * 8 + j][e], h, m, l);
            vh[g][j] = h; vm[g][j] = m; vl[g][j] = l;
        }
    size_t base = ((size_t)(half * 3) * NE + e) * DH + k0 + kl;
    #pragma unroll
    for (int g = 0; g < 4; ++g) {
        *(bf16x8*)(Bws + base                        + g * 8) = vh[g];
        *(bf16x8*)(Bws + base + (size_t)NE * DH      + g * 8) = vm[g];
        *(bf16x8*)(Bws + base + (size_t)2 * NE * DH  + g * 8) = vl[g];
    }
}

__global__ __launch_bounds__(256, 2) void torus_mfma(
    const float* __restrict__ u, const __bf16* __restrict__ Bws,
    const float* __restrict__ bias,
    const float* __restrict__ cp, const float* __restrict__ dp,
    const float* __restrict__ a1p, const float* __restrict__ b1p,
    float* __restrict__ out, float* __restrict__ esum)
{
    __shared__ float pre[4][NE][TB + 1];  // per-wave partial pre-activations, [e][t]
    __shared__ float stile[TB][NE + 1];
    __shared__ float s_m[TB], s_inv[TB];

    const int tid  = threadIdx.x;
    const int t0   = blockIdx.x * TB;
    const int lane = tid & 63;
    const int wv   = tid >> 6;
    const int half = wv >> 1;             // 0: x-half, 1: y-half
    const int kq   = wv & 1;              // k-half within the model half
    const int lr   = lane & 15;           // MFMA row (A) / col (B)
    const int lk   = (lane >> 4) * 8;     // k sub-offset within a 32-step

    unsigned abo[2];
    #pragma unroll
    for (int rt = 0; rt < 2; ++rt)
        abo[rt] = (unsigned)((t0 + rt * 16 + lr) * DM + half * DH + kq * KQ + lk);
    unsigned bbo[3][4];
    #pragma unroll
    for (int s = 0; s < 3; ++s)
        #pragma unroll
        for (int et = 0; et < 4; ++et)
            bbo[s][et] = (unsigned)(((half * 3 + s) * NE + et * 16 + lr) * DH + kq * KQ + lk);

    f32x4 acc[2][4] = {};
    f32x4 raw[2][2][2];                   // [buf][rt][q] - 2-step-deep A prefetch
    bf16x8 bh[4], bhN[4];
    #pragma unroll
    for (int rt = 0; rt < 2; ++rt) {
        raw[0][rt][0] = *(const f32x4*)(u + abo[rt]);
        raw[0][rt][1] = *(const f32x4*)(u + abo[rt] + 4);
        raw[1][rt][0] = *(const f32x4*)(u + abo[rt] + 32);
        raw[1][rt][1] = *(const f32x4*)(u + abo[rt] + 36);
    }
    #pragma unroll
    for (int et = 0; et < 4; ++et) bh[et] = *(const bf16x8*)(Bws + bbo[0][et]);

    #pragma unroll 1
    for (int ks = 0; ks < NSTEP; ++ks) {
        const int cur = ks & 1;
        // split current A step (raw[cur] -> h/m/l fragments); raw[cur] then free
        bf16x8 sh[2], sm[2], sl[2];
        #pragma unroll
        for (int rt = 0; rt < 2; ++rt)
            #pragma unroll
            for (int q = 0; q < 2; ++q)
                #pragma unroll
                for (int j = 0; j < 4; ++j) {
                    __bf16 h, m, l;
                    split3(raw[cur][rt][q][j], h, m, l);
                    sh[rt][q * 4 + j] = h; sm[rt][q * 4 + j] = m; sl[rt][q * 4 + j] = l;
                }
        const int ks2 = (ks + 2 < NSTEP) ? ks + 2 : ks;   // clamp: no OOB
        const int ks1 = (ks + 1 < NSTEP) ? ks + 1 : ks;
        #pragma unroll
        for (int rt = 0; rt < 2; ++rt) {                  // A prefetch, 2 steps ahead (HBM)
            raw[cur][rt][0] = *(const f32x4*)(u + abo[rt] + ks2 * 32);
            raw[cur][rt][1] = *(const f32x4*)(u + abo[rt] + ks2 * 32 + 4);
        }
        bf16x8 bm[4], bl[4];
        #pragma unroll
        for (int et = 0; et < 4; ++et) {                  // B: L2-hit loads
            bm[et]  = *(const bf16x8*)(Bws + bbo[1][et] + ks * 32);
            bl[et]  = *(const bf16x8*)(Bws + bbo[2][et] + ks * 32);
            bhN[et] = *(const bf16x8*)(Bws + bbo[0][et] + ks1 * 32);
        }
        // phase 1: all products against bh (latency cover for bm/bl)
        #pragma unroll
        for (int et = 0; et < 4; ++et)
            #pragma unroll
            for (int rt = 0; rt < 2; ++rt) {
                acc[rt][et] = __builtin_amdgcn_mfma_f32_16x16x32_bf16(sl[rt], bh[et], acc[rt][et], 0, 0, 0);
                acc[rt][et] = __builtin_amdgcn_mfma_f32_16x16x32_bf16(sm[rt], bh[et], acc[rt][et], 0, 0, 0);
                acc[rt][et] = __builtin_amdgcn_mfma_f32_16x16x32_bf16(sh[rt], bh[et], acc[rt][et], 0, 0, 0);
            }
        // phase 2: against bm
        #pragma unroll
        for (int et = 0; et < 4; ++et)
            #pragma unroll
            for (int rt = 0; rt < 2; ++rt) {
                acc[rt][et] = __builtin_amdgcn_mfma_f32_16x16x32_bf16(sm[rt], bm[et], acc[rt][et], 0, 0, 0);
                acc[rt][et] = __builtin_amdgcn_mfma_f32_16x16x32_bf16(sh[rt], bm[et], acc[rt][et], 0, 0, 0);
            }
        // phase 3: against bl
        #pragma unroll
        for (int et = 0; et < 4; ++et)
            #pragma unroll
            for (int rt = 0; rt < 2; ++rt)
                acc[rt][et] = __builtin_amdgcn_mfma_f32_16x16x32_bf16(sh[rt], bl[et], acc[rt][et], 0, 0, 0);
        #pragma unroll
        for (int et = 0; et < 4; ++et) bh[et] = bhN[et];
    }

    // ---- epilogue: combine wave partials, pointwise, topk, softmax ----
    __syncthreads();
    #pragma unroll
    for (int rt = 0; rt < 2; ++rt)
        #pragma unroll
        for (int et = 0; et < 4; ++et) {
            int e = et * 16 + lr;                       // D: col = lane&15
            int t = rt * 16 + ((lane >> 4) << 2);       // D: row = (lane>>4)*4 + reg
            *(f32x4*)&pre[wv][e][t] = acc[rt][et];
        }
    __syncthreads();

    {
        const float c_ = *cp, d_ = *dp, a1_ = *a1p, b1_ = *b1p;
        const int t  = tid & 31;
        const int e0 = (tid >> 5) * 8;
        #pragma unroll
        for (int i = 0; i < 8; ++i) {
            int e = e0 + i;
            float x = pre[0][e][t] + pre[1][e][t];
            float y = pre[2][e][t] + pre[3][e][t];
            x = tanhf(x) * 2.0f; y = tanhf(y) * 2.0f;
            float xa = fabsf(x), ya = fabsf(y);
            float sc = (powf(xa, a1_) + powf(ya, b1_)) *
                       expf(-(powf(xa, c_) + powf(ya, d_))) + bias[e];
            stile[t][e] = sc;
        }
    }
    __syncthreads();

    if (tid < TB) {
        const int t = tid;
        float bv[TOPK]; int bi[TOPK];
        #pragma unroll
        for (int p = 0; p < TOPK; ++p) {
            float best = -INFINITY; int besti = 0;
            for (int e = 0; e < NE; ++e) {
                float v = stile[t][e];
                bool taken = false;
                #pragma unroll
                for (int q = 0; q < p; ++q) taken = taken || (bi[q] == e);
                if (!taken && v > best) { best = v; besti = e; }  // strict > == lax.top_k tie-break
            }
            bv[p] = best; bi[p] = besti;
        }
        const float m = bv[0];
        float denom = 0.0f;
        for (int e = 0; e < NE; ++e) denom += expf(stile[t][e] - m);
        const float inv = 1.0f / denom;
        s_m[t] = m; s_inv[t] = inv;
        #pragma unroll
        for (int p = 0; p < TOPK; ++p) {
            out[OFF_TI + (size_t)(t0 + t) * TOPK + p] = (float)bi[p];
            out[OFF_TS + (size_t)(t0 + t) * TOPK + p] = bv[p];
        }
    }
    __syncthreads();

    if (tid < NE) {
        const int e = tid;
        float cs = 0.0f;
        for (int t = 0; t < TB; ++t)
            cs += expf(stile[t][e] - s_m[t]) * s_inv[t];
        atomicAdd(&esum[e], cs);
    }

    for (int idx = tid; idx < TB * NE; idx += 256)
        out[OFF_SC + (size_t)t0 * NE + idx] = stile[idx >> 6][idx & (NE - 1)];
}

__global__ __launch_bounds__(64) void torus_aux(const float* __restrict__ esum,
                                                float* __restrict__ out)
{
    const int e = threadIdx.x;
    float s = esum[e] * (1.0f / (float)N_TOK);
    float v = s * s;
    #pragma unroll
    for (int off = 32; off > 0; off >>= 1) v += __shfl_down(v, off);
    if (e == 0) out[OFF_AUX] = v * (float)NE;
}

extern "C" void kernel_launch(void* const* d_in, const int* in_sizes, int n_in,
                              void* d_out, int out_size, void* d_ws, size_t ws_size,
                              hipStream_t stream) {
    const float* u    = (const float*)d_in[0];
    const float* Ex   = (const float*)d_in[1];
    const float* Ey   = (const float*)d_in[2];
    const float* bias = (const float*)d_in[3];
    const float* cp   = (const float*)d_in[4];
    const float* dp   = (const float*)d_in[5];
    const float* a1p  = (const float*)d_in[6];
    const float* b1p  = (const float*)d_in[7];
    float* out = (float*)d_out;
    __bf16* Bws = (__bf16*)d_ws;
    float* esum = (float*)((char*)d_ws + (size_t)BSPLIT_ELEMS * sizeof(__bf16));

    prep_B<<<32, 256, 0, stream>>>(Ex, Ey, Bws);
    hipMemsetAsync(esum, 0, NE * sizeof(float), stream);
    torus_mfma<<<N_TOK / TB, 256, 0, stream>>>(u, Bws, bias, cp, dp, a1p, b1p, out, esum);
    torus_aux<<<1, 64, 0, stream>>>(esum, out);
}

// Round 4
// 131.850 us; speedup vs baseline: 1.3258x; 1.3258x over previous
//
#include <hip/hip_runtime.h>
#include <math.h>

#define N_TOK 16384
#define DM    4096
#define DH    2048
#define NE    64
#define TBK   64        // tokens per block
#define TOPK  4
#define KQ    1024      // k-range per wave (half of a model-half)
#define NSTEP 32        // KQ / 32

// out layout (all float32): topk_i [N,4] | topk_s [N,4] | scores [N,64] | aux_loss [1]
#define OFF_TI  0
#define OFF_TS  (N_TOK * TOPK)
#define OFF_SC  (N_TOK * TOPK * 2)
#define OFF_AUX (N_TOK * TOPK * 2 + N_TOK * NE)

typedef __attribute__((ext_vector_type(4)))  float  f32x4;
typedef __attribute__((ext_vector_type(16))) float  f32x16;
typedef __attribute__((ext_vector_type(8)))  __bf16 bf16x8;

// ws: __bf16 Bsplit fragment-major [h][ks64][split3][et2][sk2][lane64][8] (1.5 MB), then float esum[64]
#define BSPLIT_ELEMS (2 * 64 * 3 * 2 * 2 * 64 * 8)

__device__ __forceinline__ void split3(float a, __bf16& h, __bf16& m, __bf16& l) {
    h = (__bf16)a;                 // a = h+m+l EXACT (24 = 8+8+8 mantissa bits)
    float r = a - (float)h;
    m = (__bf16)r;
    float r2 = r - (float)m;
    l = (__bf16)r2;
}

// One thread per (h, ks, et, sk, lane): split 8 consecutive k of one expert column,
// write 3 bf16x8 fragments in MFMA-fragment-major order.
__global__ __launch_bounds__(256) void prep_B(
    const float* __restrict__ Ex, const float* __restrict__ Ey,
    __bf16* __restrict__ Bws)
{
    const int t    = blockIdx.x * 256 + threadIdx.x;   // 32768 threads
    const int lane = t & 63;
    const int sk   = (t >> 6) & 1;
    const int et   = (t >> 7) & 1;
    const int ks   = (t >> 8) & 63;
    const int h    = (t >> 14) & 1;
    const float* E = h ? Ey : Ex;
    const int e  = et * 32 + (lane & 31);
    const int k0 = ks * 32 + sk * 16 + (lane >> 5) * 8;
    bf16x8 vh, vm, vl;
    #pragma unroll
    for (int j = 0; j < 8; ++j) {
        __bf16 hh, mm, ll;
        split3(E[(size_t)(k0 + j) * NE + e], hh, mm, ll);
        vh[j] = hh; vm[j] = mm; vl[j] = ll;
    }
    // idx(h,ks,split,et,sk,lane) = (((((h*64+ks)*3+split)*2+et)*2+sk)*64+lane)*8
    #pragma unroll
    for (int s = 0; s < 3; ++s) {
        size_t base = ((((((size_t)h * 64 + ks) * 3 + s) * 2 + et) * 2 + sk) * 64 + lane) * 8;
        *(bf16x8*)(Bws + base) = (s == 0) ? vh : (s == 1) ? vm : vl;
    }
}

__global__ __launch_bounds__(512, 2) void torus_mfma(
    const float* __restrict__ u, const __bf16* __restrict__ Bws,
    const float* __restrict__ bias,
    const float* __restrict__ cp, const float* __restrict__ dp,
    const float* __restrict__ a1p, const float* __restrict__ b1p,
    float* __restrict__ out, float* __restrict__ esum)
{
    __shared__ float pre[2][NE][68];      // [half][e][tok] combined pre-activations
    __shared__ float stile[TBK][NE + 1];
    __shared__ float s_m[TBK], s_inv[TBK];

    const int tid  = threadIdx.x;
    const int t0   = blockIdx.x * TBK;
    const int lane = tid & 63;
    const int wv   = tid >> 6;            // 0..7
    const int h    = wv >> 2;             // model half (x / y)
    const int kh   = (wv >> 1) & 1;       // k-half within the model half
    const int th   = wv & 1;              // token half (32 tokens)
    const int lr   = lane & 31;           // MFMA A-row (token) / B-col (expert)
    const int lkh  = lane >> 5;           // k-subgroup within fragment

    // A: row-major u, per-lane base; 32 fp32 per step per lane-row segment
    const float* ap = u + (size_t)(t0 + th * 32 + lr) * DM + h * DH + kh * KQ + lkh * 8;
    // B: fragment-major split workspace; 12 fragments (512 elems apart) per step
    const __bf16* bp0 = Bws + ((size_t)h * 64 + kh * 32) * 6144 + lane * 8;

    f32x16 acc[2] = {};                   // [et] 32tok x 32e each
    f32x4  rA[2][4];                      // [buf][sk0lo,sk0hi,sk1lo,sk1hi] - STATIC indexed

    auto load_raw = [&](f32x4 (&r)[4], int s) {
        const float* p = ap + s * 32;
        r[0] = *(const f32x4*)(p);
        r[1] = *(const f32x4*)(p + 4);
        r[2] = *(const f32x4*)(p + 16);
        r[3] = *(const f32x4*)(p + 20);
    };

    auto step = [&](int s, f32x4 (&r)[4]) {
        // 1) issue B loads for this step (L2-hot), in MFMA consumption order
        const __bf16* bp = bp0 + (size_t)s * 6144;
        bf16x8 bh[2][2], bm[2][2], bl[2][2];
        #pragma unroll
        for (int et = 0; et < 2; ++et)
            #pragma unroll
            for (int sk = 0; sk < 2; ++sk) {
                bh[et][sk] = *(const bf16x8*)(bp + (0 * 4 + et * 2 + sk) * 512);
                bm[et][sk] = *(const bf16x8*)(bp + (1 * 4 + et * 2 + sk) * 512);
                bl[et][sk] = *(const bf16x8*)(bp + (2 * 4 + et * 2 + sk) * 512);
            }
        // 2) split current A (covers B L2 latency with VALU work)
        bf16x8 sh[2], sm[2], sl[2];
        #pragma unroll
        for (int sk = 0; sk < 2; ++sk)
            #pragma unroll
            for (int q = 0; q < 2; ++q)
                #pragma unroll
                for (int j = 0; j < 4; ++j) {
                    __bf16 hh, mm, ll;
                    split3(r[sk * 2 + q][j], hh, mm, ll);
                    sh[sk][q * 4 + j] = hh; sm[sk][q * 4 + j] = mm; sl[sk][q * 4 + j] = ll;
                }
        // 3) A prefetch 2 steps ahead into the buffer just consumed (HBM latency cover)
        const int sp = (s + 2 < NSTEP) ? s + 2 : s;
        load_raw(r, sp);
        // 4) MFMA: 6 exact products, ordered to consume bh -> bm -> bl as they arrive
        #pragma unroll
        for (int et = 0; et < 2; ++et)
            #pragma unroll
            for (int sk = 0; sk < 2; ++sk) {
                acc[et] = __builtin_amdgcn_mfma_f32_32x32x16_bf16(sh[sk], bh[et][sk], acc[et], 0, 0, 0);
                acc[et] = __builtin_amdgcn_mfma_f32_32x32x16_bf16(sm[sk], bh[et][sk], acc[et], 0, 0, 0);
                acc[et] = __builtin_amdgcn_mfma_f32_32x32x16_bf16(sl[sk], bh[et][sk], acc[et], 0, 0, 0);
            }
        #pragma unroll
        for (int et = 0; et < 2; ++et)
            #pragma unroll
            for (int sk = 0; sk < 2; ++sk) {
                acc[et] = __builtin_amdgcn_mfma_f32_32x32x16_bf16(sh[sk], bm[et][sk], acc[et], 0, 0, 0);
                acc[et] = __builtin_amdgcn_mfma_f32_32x32x16_bf16(sm[sk], bm[et][sk], acc[et], 0, 0, 0);
            }
        #pragma unroll
        for (int et = 0; et < 2; ++et)
            #pragma unroll
            for (int sk = 0; sk < 2; ++sk)
                acc[et] = __builtin_amdgcn_mfma_f32_32x32x16_bf16(sh[sk], bl[et][sk], acc[et], 0, 0, 0);
    };

    load_raw(rA[0], 0);
    load_raw(rA[1], 1);
    #pragma unroll 1
    for (int s = 0; s < NSTEP; s += 2) {
        step(s,     rA[0]);
        step(s + 1, rA[1]);
    }

    // ---- combine kh partials in LDS: C/D layout col=lane&31, row=(reg&3)+8*(reg>>2)+4*(lane>>5)
    __syncthreads();
    if (kh == 0) {
        #pragma unroll
        for (int et = 0; et < 2; ++et)
            #pragma unroll
            for (int q = 0; q < 4; ++q) {
                int e  = et * 32 + lr;
                int tk = th * 32 + q * 8 + 4 * lkh;
                f32x4 v = { acc[et][q*4+0], acc[et][q*4+1], acc[et][q*4+2], acc[et][q*4+3] };
                *(f32x4*)&pre[h][e][tk] = v;
            }
    }
    __syncthreads();
    if (kh == 1) {
        #pragma unroll
        for (int et = 0; et < 2; ++et)
            #pragma unroll
            for (int q = 0; q < 4; ++q) {
                int e  = et * 32 + lr;
                int tk = th * 32 + q * 8 + 4 * lkh;
                f32x4 v = { acc[et][q*4+0], acc[et][q*4+1], acc[et][q*4+2], acc[et][q*4+3] };
                f32x4 o = *(f32x4*)&pre[h][e][tk];
                v += o;
                *(f32x4*)&pre[h][e][tk] = v;
            }
    }
    __syncthreads();

    // ---- pointwise torus map: 512 threads x 8 (tok, e) each
    {
        const float c_ = *cp, d_ = *dp, a1_ = *a1p, b1_ = *b1p;
        const int tk = tid & 63;
        const int e0 = (tid >> 6) * 8;
        #pragma unroll
        for (int i = 0; i < 8; ++i) {
            int e = e0 + i;
            float x = pre[0][e][tk];
            float y = pre[1][e][tk];
            x = tanhf(x) * 2.0f; y = tanhf(y) * 2.0f;
            float xa = fabsf(x), ya = fabsf(y);
            float sc = (powf(xa, a1_) + powf(ya, b1_)) *
                       expf(-(powf(xa, c_) + powf(ya, d_))) + bias[e];
            stile[tk][e] = sc;
        }
    }
    __syncthreads();

    // ---- per-token top-4 + softmax denom
    if (tid < TBK) {
        const int t = tid;
        float bv[TOPK]; int bi[TOPK];
        #pragma unroll
        for (int p = 0; p < TOPK; ++p) {
            float best = -INFINITY; int besti = 0;
            for (int e = 0; e < NE; ++e) {
                float v = stile[t][e];
                bool taken = false;
                #pragma unroll
                for (int q = 0; q < p; ++q) taken = taken || (bi[q] == e);
                if (!taken && v > best) { best = v; besti = e; }  // strict > == lax.top_k tie-break
            }
            bv[p] = best; bi[p] = besti;
        }
        const float m = bv[0];
        float denom = 0.0f;
        for (int e = 0; e < NE; ++e) denom += expf(stile[t][e] - m);
        const float inv = 1.0f / denom;
        s_m[t] = m; s_inv[t] = inv;
        #pragma unroll
        for (int p = 0; p < TOPK; ++p) {
            out[OFF_TI + (size_t)(t0 + t) * TOPK + p] = (float)bi[p];
            out[OFF_TS + (size_t)(t0 + t) * TOPK + p] = bv[p];
        }
    }
    __syncthreads();

    // ---- per-expert prob column-sums -> global accumulate
    if (tid < NE) {
        const int e = tid;
        float cs = 0.0f;
        for (int t = 0; t < TBK; ++t)
            cs += expf(stile[t][e] - s_m[t]) * s_inv[t];
        atomicAdd(&esum[e], cs);
    }

    // ---- scores -> global, coalesced
    for (int idx = tid; idx < TBK * NE; idx += 512)
        out[OFF_SC + (size_t)t0 * NE + idx] = stile[idx >> 6][idx & (NE - 1)];
}

__global__ __launch_bounds__(64) void torus_aux(const float* __restrict__ esum,
                                                float* __restrict__ out)
{
    const int e = threadIdx.x;
    float s = esum[e] * (1.0f / (float)N_TOK);
    float v = s * s;
    #pragma unroll
    for (int off = 32; off > 0; off >>= 1) v += __shfl_down(v, off);
    if (e == 0) out[OFF_AUX] = v * (float)NE;
}

extern "C" void kernel_launch(void* const* d_in, const int* in_sizes, int n_in,
                              void* d_out, int out_size, void* d_ws, size_t ws_size,
                              hipStream_t stream) {
    const float* u    = (const float*)d_in[0];
    const float* Ex   = (const float*)d_in[1];
    const float* Ey   = (const float*)d_in[2];
    const float* bias = (const float*)d_in[3];
    const float* cp   = (const float*)d_in[4];
    const float* dp   = (const float*)d_in[5];
    const float* a1p  = (const float*)d_in[6];
    const float* b1p  = (const float*)d_in[7];
    float* out = (float*)d_out;
    __bf16* Bws = (__bf16*)d_ws;
    float* esum = (float*)((char*)d_ws + (size_t)BSPLIT_ELEMS * sizeof(__bf16));

    prep_B<<<128, 256, 0, stream>>>(Ex, Ey, Bws);
    hipMemsetAsync(esum, 0, NE * sizeof(float), stream);
    torus_mfma<<<N_TOK / TBK, 512, 0, stream>>>(u, Bws, bias, cp, dp, a1p, b1p, out, esum);
    torus_aux<<<1, 64, 0, stream>>>(esum, out);
}

// Round 5
// 124.048 us; speedup vs baseline: 1.4092x; 1.0629x over previous
//
#include <hip/hip_runtime.h>
#include <math.h>

#define N_TOK 16384
#define DM    4096
#define DH    2048
#define NE    64
#define TBK   64        // tokens per block
#define TOPK  4
#define KQ    1024      // k-range per wave (half of a model-half)
#define NSTEP 32        // KQ / 32

// out layout (all float32): topk_i [N,4] | topk_s [N,4] | scores [N,64] | aux_loss [1]
#define OFF_TI  0
#define OFF_TS  (N_TOK * TOPK)
#define OFF_SC  (N_TOK * TOPK * 2)
#define OFF_AUX (N_TOK * TOPK * 2 + N_TOK * NE)

typedef __attribute__((ext_vector_type(4)))  float  f32x4;
typedef __attribute__((ext_vector_type(16))) float  f32x16;
typedef __attribute__((ext_vector_type(8)))  __bf16 bf16x8;

// ws: __bf16 Bsplit fragment-major [h][ks64][split3][et2][sk2][lane64][8] (1.5 MB), then float esum[64]
#define BSPLIT_ELEMS (2 * 64 * 3 * 2 * 2 * 64 * 8)

__device__ __forceinline__ void split3(float a, __bf16& h, __bf16& m, __bf16& l) {
    h = (__bf16)a;                 // a = h+m+l EXACT (24 = 8+8+8 mantissa bits)
    float r = a - (float)h;
    m = (__bf16)r;
    float r2 = r - (float)m;
    l = (__bf16)r2;
}

// One thread per (h, ks, et, sk, lane): split 8 consecutive k of one expert column,
// write 3 bf16x8 fragments in MFMA-fragment-major order.
__global__ __launch_bounds__(256) void prep_B(
    const float* __restrict__ Ex, const float* __restrict__ Ey,
    __bf16* __restrict__ Bws)
{
    const int t    = blockIdx.x * 256 + threadIdx.x;   // 32768 threads
    const int lane = t & 63;
    const int sk   = (t >> 6) & 1;
    const int et   = (t >> 7) & 1;
    const int ks   = (t >> 8) & 63;
    const int h    = (t >> 14) & 1;
    const float* E = h ? Ey : Ex;
    const int e  = et * 32 + (lane & 31);
    const int k0 = ks * 32 + sk * 16 + (lane >> 5) * 8;
    bf16x8 vh, vm, vl;
    #pragma unroll
    for (int j = 0; j < 8; ++j) {
        __bf16 hh, mm, ll;
        split3(E[(size_t)(k0 + j) * NE + e], hh, mm, ll);
        vh[j] = hh; vm[j] = mm; vl[j] = ll;
    }
    #pragma unroll
    for (int s = 0; s < 3; ++s) {
        size_t base = ((((((size_t)h * 64 + ks) * 3 + s) * 2 + et) * 2 + sk) * 64 + lane) * 8;
        *(bf16x8*)(Bws + base) = (s == 0) ? vh : (s == 1) ? vm : vl;
    }
}

__global__ __launch_bounds__(512, 2) void torus_mfma(
    const float* __restrict__ u, const __bf16* __restrict__ Bws,
    const float* __restrict__ bias,
    const float* __restrict__ cp, const float* __restrict__ dp,
    const float* __restrict__ a1p, const float* __restrict__ b1p,
    float* __restrict__ out, float* __restrict__ esum)
{
    __shared__ float pre[2][NE][68];      // [half][e][tok] combined pre-activations
    __shared__ float stile[TBK][NE + 1];
    __shared__ float s_m[TBK], s_inv[TBK];

    const int tid  = threadIdx.x;
    const int t0   = blockIdx.x * TBK;
    const int lane = tid & 63;
    const int wv   = tid >> 6;            // 0..7
    const int h    = wv >> 2;             // model half (x / y)
    const int kh   = (wv >> 1) & 1;       // k-half within the model half
    const int th   = wv & 1;              // token half (32 tokens)
    const int lr   = lane & 31;           // MFMA A-row (token) / B-col (expert)
    const int lkh  = lane >> 5;           // k-subgroup within fragment

    const float* ap = u + (size_t)(t0 + th * 32 + lr) * DM + h * DH + kh * KQ + lkh * 8;
    const __bf16* bp0 = Bws + ((size_t)h * 64 + kh * 32) * 6144 + lane * 8;

    f32x16 acc[2][2] = {};                // [sk][et] independent chains; summed in epilogue
    f32x4  rA[2][4];                      // [buf][...] static-indexed 2-step A prefetch

    auto load_raw = [&](f32x4 (&r)[4], int s) {
        const float* p = ap + s * 32;
        r[0] = *(const f32x4*)(p);
        r[1] = *(const f32x4*)(p + 4);
        r[2] = *(const f32x4*)(p + 16);
        r[3] = *(const f32x4*)(p + 20);
    };

    auto step = [&](int s, f32x4 (&r)[4]) {
        // ---- 1) B loads FIRST (oldest in vmcnt order; L2-hot) ----
        const __bf16* bp = bp0 + (size_t)s * 6144;
        bf16x8 bh[2][2], bm[2][2], bl[2][2];
        #pragma unroll
        for (int et = 0; et < 2; ++et)
            #pragma unroll
            for (int sk = 0; sk < 2; ++sk) {
                bh[et][sk] = *(const bf16x8*)(bp + (0 * 4 + et * 2 + sk) * 512);
                bm[et][sk] = *(const bf16x8*)(bp + (1 * 4 + et * 2 + sk) * 512);
                bl[et][sk] = *(const bf16x8*)(bp + (2 * 4 + et * 2 + sk) * 512);
            }
        __builtin_amdgcn_sched_barrier(0);   // pin: B loads issued before anything below
        // ---- 2) split current A (VALU; covers B L2 latency; waits only on 2-step-old A) ----
        bf16x8 sh[2], sm[2], sl[2];
        #pragma unroll
        for (int sk = 0; sk < 2; ++sk)
            #pragma unroll
            for (int q = 0; q < 2; ++q)
                #pragma unroll
                for (int j = 0; j < 4; ++j) {
                    __bf16 hh, mm, ll;
                    split3(r[sk * 2 + q][j], hh, mm, ll);
                    sh[sk][q * 4 + j] = hh; sm[sk][q * 4 + j] = mm; sl[sk][q * 4 + j] = ll;
                }
        // ---- 3) A prefetch 2 steps ahead into the just-freed buffer (newest; HBM) ----
        const int sp = (s + 2 < NSTEP) ? s + 2 : s;
        load_raw(r, sp);
        __builtin_amdgcn_sched_barrier(0);   // pin: split+prefetch stay above the MFMA block
        // ---- 4) MFMA: 6 exact products; consume bh -> bm -> bl (bl wait skips A prefetch) ----
        #pragma unroll
        for (int et = 0; et < 2; ++et)
            #pragma unroll
            for (int sk = 0; sk < 2; ++sk) {
                acc[sk][et] = __builtin_amdgcn_mfma_f32_32x32x16_bf16(sh[sk], bh[et][sk], acc[sk][et], 0, 0, 0);
                acc[sk][et] = __builtin_amdgcn_mfma_f32_32x32x16_bf16(sm[sk], bh[et][sk], acc[sk][et], 0, 0, 0);
                acc[sk][et] = __builtin_amdgcn_mfma_f32_32x32x16_bf16(sl[sk], bh[et][sk], acc[sk][et], 0, 0, 0);
            }
        #pragma unroll
        for (int et = 0; et < 2; ++et)
            #pragma unroll
            for (int sk = 0; sk < 2; ++sk) {
                acc[sk][et] = __builtin_amdgcn_mfma_f32_32x32x16_bf16(sh[sk], bm[et][sk], acc[sk][et], 0, 0, 0);
                acc[sk][et] = __builtin_amdgcn_mfma_f32_32x32x16_bf16(sm[sk], bm[et][sk], acc[sk][et], 0, 0, 0);
            }
        #pragma unroll
        for (int et = 0; et < 2; ++et)
            #pragma unroll
            for (int sk = 0; sk < 2; ++sk)
                acc[sk][et] = __builtin_amdgcn_mfma_f32_32x32x16_bf16(sh[sk], bl[et][sk], acc[sk][et], 0, 0, 0);
        __builtin_amdgcn_sched_barrier(0);   // step boundary
    };

    load_raw(rA[0], 0);
    load_raw(rA[1], 1);
    #pragma unroll 1
    for (int s = 0; s < NSTEP; s += 2) {
        step(s,     rA[0]);
        step(s + 1, rA[1]);
    }

    // ---- combine sk chains, then kh partials in LDS ----
    // C/D layout: col=lane&31, row=(reg&3)+8*(reg>>2)+4*(lane>>5)
    __syncthreads();
    if (kh == 0) {
        #pragma unroll
        for (int et = 0; et < 2; ++et) {
            f32x16 a = acc[0][et] + acc[1][et];
            #pragma unroll
            for (int q = 0; q < 4; ++q) {
                int e  = et * 32 + lr;
                int tk = th * 32 + q * 8 + 4 * lkh;
                f32x4 v = { a[q*4+0], a[q*4+1], a[q*4+2], a[q*4+3] };
                *(f32x4*)&pre[h][e][tk] = v;
            }
        }
    }
    __syncthreads();
    if (kh == 1) {
        #pragma unroll
        for (int et = 0; et < 2; ++et) {
            f32x16 a = acc[0][et] + acc[1][et];
            #pragma unroll
            for (int q = 0; q < 4; ++q) {
                int e  = et * 32 + lr;
                int tk = th * 32 + q * 8 + 4 * lkh;
                f32x4 v = { a[q*4+0], a[q*4+1], a[q*4+2], a[q*4+3] };
                f32x4 o = *(f32x4*)&pre[h][e][tk];
                v += o;
                *(f32x4*)&pre[h][e][tk] = v;
            }
        }
    }
    __syncthreads();

    // ---- pointwise torus map ----
    {
        const float c_ = *cp, d_ = *dp, a1_ = *a1p, b1_ = *b1p;
        const int tk = tid & 63;
        const int e0 = (tid >> 6) * 8;
        #pragma unroll
        for (int i = 0; i < 8; ++i) {
            int e = e0 + i;
            float x = pre[0][e][tk];
            float y = pre[1][e][tk];
            x = tanhf(x) * 2.0f; y = tanhf(y) * 2.0f;
            float xa = fabsf(x), ya = fabsf(y);
            float sc = (powf(xa, a1_) + powf(ya, b1_)) *
                       expf(-(powf(xa, c_) + powf(ya, d_))) + bias[e];
            stile[tk][e] = sc;
        }
    }
    __syncthreads();

    // ---- per-token top-4 + softmax denom ----
    if (tid < TBK) {
        const int t = tid;
        float bv[TOPK]; int bi[TOPK];
        #pragma unroll
        for (int p = 0; p < TOPK; ++p) {
            float best = -INFINITY; int besti = 0;
            for (int e = 0; e < NE; ++e) {
                float v = stile[t][e];
                bool taken = false;
                #pragma unroll
                for (int q = 0; q < p; ++q) taken = taken || (bi[q] == e);
                if (!taken && v > best) { best = v; besti = e; }  // strict > == lax.top_k tie-break
            }
            bv[p] = best; bi[p] = besti;
        }
        const float m = bv[0];
        float denom = 0.0f;
        for (int e = 0; e < NE; ++e) denom += expf(stile[t][e] - m);
        const float inv = 1.0f / denom;
        s_m[t] = m; s_inv[t] = inv;
        #pragma unroll
        for (int p = 0; p < TOPK; ++p) {
            out[OFF_TI + (size_t)(t0 + t) * TOPK + p] = (float)bi[p];
            out[OFF_TS + (size_t)(t0 + t) * TOPK + p] = bv[p];
        }
    }
    __syncthreads();

    // ---- per-expert prob column-sums -> global accumulate ----
    if (tid < NE) {
        const int e = tid;
        float cs = 0.0f;
        for (int t = 0; t < TBK; ++t)
            cs += expf(stile[t][e] - s_m[t]) * s_inv[t];
        atomicAdd(&esum[e], cs);
    }

    // ---- scores -> global, coalesced ----
    for (int idx = tid; idx < TBK * NE; idx += 512)
        out[OFF_SC + (size_t)t0 * NE + idx] = stile[idx >> 6][idx & (NE - 1)];
}

__global__ __launch_bounds__(64) void torus_aux(const float* __restrict__ esum,
                                                float* __restrict__ out)
{
    const int e = threadIdx.x;
    float s = esum[e] * (1.0f / (float)N_TOK);
    float v = s * s;
    #pragma unroll
    for (int off = 32; off > 0; off >>= 1) v += __shfl_down(v, off);
    if (e == 0) out[OFF_AUX] = v * (float)NE;
}

extern "C" void kernel_launch(void* const* d_in, const int* in_sizes, int n_in,
                              void* d_out, int out_size, void* d_ws, size_t ws_size,
                              hipStream_t stream) {
    const float* u    = (const float*)d_in[0];
    const float* Ex   = (const float*)d_in[1];
    const float* Ey   = (const float*)d_in[2];
    const float* bias = (const float*)d_in[3];
    const float* cp   = (const float*)d_in[4];
    const float* dp   = (const float*)d_in[5];
    const float* a1p  = (const float*)d_in[6];
    const float* b1p  = (const float*)d_in[7];
    float* out = (float*)d_out;
    __bf16* Bws = (__bf16*)d_ws;
    float* esum = (float*)((char*)d_ws + (size_t)BSPLIT_ELEMS * sizeof(__bf16));

    prep_B<<<128, 256, 0, stream>>>(Ex, Ey, Bws);
    hipMemsetAsync(esum, 0, NE * sizeof(float), stream);
    torus_mfma<<<N_TOK / TBK, 512, 0, stream>>>(u, Bws, bias, cp, dp, a1p, b1p, out, esum);
    torus_aux<<<1, 64, 0, stream>>>(esum, out);
}